// Round 1
// baseline (489.666 us; speedup 1.0000x reference)
//
#include <hip/hip_runtime.h>

#define SDIM 10
#define HDIM 2048
#define LDIM 4096
#define BDIM 4

// 1/sqrt(2048)
#define KSCALE 0.02209708691207961f

// ---------------------------------------------------------------------------
// Kernel 1: k[b,s,o] = sum_h h_l[b,s,h]*w_k[o,h];  v likewise with w_v.
// One wave per (o-pair, b). Wave reads w rows coalesced (lane i -> float4 i),
// butterfly-reduces 20 dots (10 s x 2 o) per matrix.
// grid (256, 4) x block 256 (4 waves) -> 1024 waves/batch covering o in pairs.
// ---------------------------------------------------------------------------
__global__ __launch_bounds__(256) void kv_kernel(
    const float* __restrict__ h_l, const float* __restrict__ w_k,
    const float* __restrict__ w_v, float* __restrict__ k_out,
    float* __restrict__ v_out) {
  const int b = blockIdx.y;
  const int wave = threadIdx.x >> 6;
  const int lane = threadIdx.x & 63;
  const int opair = blockIdx.x * 4 + wave;
  const int o0 = opair * 2;

  const float4* hl4 = (const float4*)(h_l + (size_t)b * SDIM * HDIM);
  const float4* wk0 = (const float4*)(w_k + (size_t)o0 * HDIM);
  const float4* wk1 = (const float4*)(w_k + (size_t)(o0 + 1) * HDIM);
  const float4* wv0 = (const float4*)(w_v + (size_t)o0 * HDIM);
  const float4* wv1 = (const float4*)(w_v + (size_t)(o0 + 1) * HDIM);

  float ak0[SDIM], ak1[SDIM], av0[SDIM], av1[SDIM];
#pragma unroll
  for (int s = 0; s < SDIM; s++) { ak0[s] = ak1[s] = av0[s] = av1[s] = 0.f; }

#pragma unroll
  for (int j = 0; j < 8; j++) {
    const int idx = j * 64 + lane;
    const float4 a0 = wk0[idx], a1 = wk1[idx];
    const float4 c0 = wv0[idx], c1 = wv1[idx];
#pragma unroll
    for (int s = 0; s < SDIM; s++) {
      const float4 h = hl4[s * 512 + idx];
      ak0[s] += a0.x * h.x + a0.y * h.y + a0.z * h.z + a0.w * h.w;
      ak1[s] += a1.x * h.x + a1.y * h.y + a1.z * h.z + a1.w * h.w;
      av0[s] += c0.x * h.x + c0.y * h.y + c0.z * h.z + c0.w * h.w;
      av1[s] += c1.x * h.x + c1.y * h.y + c1.z * h.z + c1.w * h.w;
    }
  }
#pragma unroll
  for (int s = 0; s < SDIM; s++) {
#pragma unroll
    for (int d = 1; d < 64; d <<= 1) {
      ak0[s] += __shfl_xor(ak0[s], d);
      ak1[s] += __shfl_xor(ak1[s], d);
      av0[s] += __shfl_xor(av0[s], d);
      av1[s] += __shfl_xor(av1[s], d);
    }
  }
  if (lane == 0) {
#pragma unroll
    for (int s = 0; s < SDIM; s++) {
      const size_t base = ((size_t)b * SDIM + s) * HDIM + o0;
      k_out[base]     = ak0[s];
      k_out[base + 1] = ak1[s];
      v_out[base]     = av0[s];
      v_out[base + 1] = av1[s];
    }
  }
}

// ---------------------------------------------------------------------------
// Kernel 2a: kk partials. kk[b,s,h] = sum_o k[b,s,o]*w_q[o,h].
// Output-stationary: thread -> float4 of h (w_q reads fully coalesced),
// k scalars broadcast from LDS. o split into 16 chunks of 128, s into halves
// of 5 -> grid (2 htile, 32 oc*shalf, 4 b) = 256 blocks. Partials to ws.
// ---------------------------------------------------------------------------
#define OSPLIT 16
__global__ __launch_bounds__(256) void kk_part_kernel(
    const float* __restrict__ k_in, const float* __restrict__ w_q,
    float* __restrict__ part) {
  const int b = blockIdx.z;
  const int oc = blockIdx.y >> 1;
  const int s0 = (blockIdx.y & 1) * 5;
  const int f4 = blockIdx.x * 256 + threadIdx.x;  // float4 index in [0,512)

  __shared__ float ksh[5 * 128];
  for (int idx = threadIdx.x; idx < 5 * 128; idx += 256) {
    const int s = idx >> 7, oo = idx & 127;
    ksh[idx] = k_in[((size_t)b * SDIM + s0 + s) * HDIM + oc * 128 + oo];
  }
  __syncthreads();

  float4 acc[5];
#pragma unroll
  for (int s = 0; s < 5; s++) acc[s] = make_float4(0.f, 0.f, 0.f, 0.f);

  const float4* wq4 = (const float4*)w_q;
  for (int oo = 0; oo < 128; oo++) {
    const float4 w = wq4[(size_t)(oc * 128 + oo) * 512 + f4];
#pragma unroll
    for (int s = 0; s < 5; s++) {
      const float kv = ksh[s * 128 + oo];
      acc[s].x += kv * w.x; acc[s].y += kv * w.y;
      acc[s].z += kv * w.z; acc[s].w += kv * w.w;
    }
  }
#pragma unroll
  for (int s = 0; s < 5; s++) {
    ((float4*)part)[(((size_t)oc * BDIM + b) * SDIM + s0 + s) * 512 + f4] = acc[s];
  }
}

// Kernel 2b: reduce 16 partials -> kk. 20480 float4 outputs.
__global__ __launch_bounds__(256) void kk_reduce_kernel(
    const float* __restrict__ part, float* __restrict__ kk_out) {
  const int t = blockIdx.x * 256 + threadIdx.x;  // [0, 20480)
  const float4* p4 = (const float4*)part;
  float4 acc = make_float4(0.f, 0.f, 0.f, 0.f);
#pragma unroll
  for (int p = 0; p < OSPLIT; p++) {
    const float4 v = p4[(size_t)p * 20480 + t];
    acc.x += v.x; acc.y += v.y; acc.z += v.z; acc.w += v.w;
  }
  ((float4*)kk_out)[t] = acc;
}

// ---------------------------------------------------------------------------
// Kernel 3: vo[b,s,o] = sum_h v[b,s,h]*w_o[o,h]. Same wave-per-(o-pair,b)
// structure as kernel 1, single matrix.
// ---------------------------------------------------------------------------
__global__ __launch_bounds__(256) void vo_kernel(
    const float* __restrict__ v_in, const float* __restrict__ w_o,
    float* __restrict__ vo_out) {
  const int b = blockIdx.y;
  const int wave = threadIdx.x >> 6;
  const int lane = threadIdx.x & 63;
  const int opair = blockIdx.x * 4 + wave;
  const int o0 = opair * 2;

  const float4* vb4 = (const float4*)(v_in + (size_t)b * SDIM * HDIM);
  const float4* wo0 = (const float4*)(w_o + (size_t)o0 * HDIM);
  const float4* wo1 = (const float4*)(w_o + (size_t)(o0 + 1) * HDIM);

  float a0[SDIM], a1[SDIM];
#pragma unroll
  for (int s = 0; s < SDIM; s++) { a0[s] = a1[s] = 0.f; }

#pragma unroll
  for (int j = 0; j < 8; j++) {
    const int idx = j * 64 + lane;
    const float4 w0 = wo0[idx], w1 = wo1[idx];
#pragma unroll
    for (int s = 0; s < SDIM; s++) {
      const float4 h = vb4[s * 512 + idx];
      a0[s] += w0.x * h.x + w0.y * h.y + w0.z * h.z + w0.w * h.w;
      a1[s] += w1.x * h.x + w1.y * h.y + w1.z * h.z + w1.w * h.w;
    }
  }
#pragma unroll
  for (int s = 0; s < SDIM; s++) {
#pragma unroll
    for (int d = 1; d < 64; d <<= 1) {
      a0[s] += __shfl_xor(a0[s], d);
      a1[s] += __shfl_xor(a1[s], d);
    }
  }
  if (lane == 0) {
#pragma unroll
    for (int s = 0; s < SDIM; s++) {
      const size_t base = ((size_t)b * SDIM + s) * HDIM + o0;
      vo_out[base]     = a0[s];
      vo_out[base + 1] = a1[s];
    }
  }
}

// ---------------------------------------------------------------------------
// Kernel 4 (main): per row l: scores = h_e . kk / sqrt(H); p = softmax;
// out = h_e + alpha * sum_s p_s * vo_s.
// v2: 4 rows per wave (was 2) -> kk/vo L2 re-read volume halves (1.31 GB ->
// 655 MB) and FMA per loaded float4 doubles. he[4][8] = 128 VGPR; bound at
// 2 waves/SIMD. block 256 (4 waves, 16 rows), grid (256, 4) = 1024 blocks.
// ---------------------------------------------------------------------------
__global__ __launch_bounds__(256, 2) void attn_kernel(
    const float* __restrict__ h_e, const float* __restrict__ kk,
    const float* __restrict__ vo, const float* __restrict__ alpha_p,
    float* __restrict__ out) {
  const int b = blockIdx.y;
  const int wave = threadIdx.x >> 6;
  const int lane = threadIdx.x & 63;
  const int row0 = blockIdx.x * 16 + wave * 4;
  const float alpha = *alpha_p;
  const float4* kkb = (const float4*)(kk + (size_t)b * SDIM * HDIM);
  const float4* vob = (const float4*)(vo + (size_t)b * SDIM * HDIM);
  const size_t rowbase = ((size_t)b * LDIM + row0) * HDIM;

  float4 he[4][8];
#pragma unroll
  for (int r = 0; r < 4; r++) {
    const float4* src = (const float4*)(h_e + rowbase + (size_t)r * HDIM);
#pragma unroll
    for (int i = 0; i < 8; i++) he[r][i] = src[i * 64 + lane];
  }

  float acc[4][SDIM];
#pragma unroll
  for (int r = 0; r < 4; r++)
#pragma unroll
    for (int s = 0; s < SDIM; s++) acc[r][s] = 0.f;

#pragma unroll
  for (int i = 0; i < 8; i++) {
#pragma unroll
    for (int s = 0; s < SDIM; s++) {
      const float4 kv = kkb[s * 512 + i * 64 + lane];
#pragma unroll
      for (int r = 0; r < 4; r++)
        acc[r][s] += he[r][i].x * kv.x + he[r][i].y * kv.y +
                     he[r][i].z * kv.z + he[r][i].w * kv.w;
    }
  }

#pragma unroll
  for (int r = 0; r < 4; r++)
#pragma unroll
    for (int s = 0; s < SDIM; s++) {
      float v = acc[r][s];
      v += __shfl_xor(v, 1);
      v += __shfl_xor(v, 2);
      v += __shfl_xor(v, 4);
      v += __shfl_xor(v, 8);
      v += __shfl_xor(v, 16);
      v += __shfl_xor(v, 32);
      acc[r][s] = v * KSCALE;
    }

#pragma unroll
  for (int r = 0; r < 4; r++) {
    float m = acc[r][0];
#pragma unroll
    for (int s = 1; s < SDIM; s++) m = fmaxf(m, acc[r][s]);
    float sum = 0.f;
#pragma unroll
    for (int s = 0; s < SDIM; s++) {
      acc[r][s] = __expf(acc[r][s] - m);
      sum += acc[r][s];
    }
    const float inv = alpha / sum;
#pragma unroll
    for (int s = 0; s < SDIM; s++) acc[r][s] *= inv;
  }

#pragma unroll
  for (int i = 0; i < 8; i++) {
    float4 o4[4];
#pragma unroll
    for (int r = 0; r < 4; r++) o4[r] = he[r][i];
#pragma unroll
    for (int s = 0; s < SDIM; s++) {
      const float4 vv = vob[s * 512 + i * 64 + lane];
#pragma unroll
      for (int r = 0; r < 4; r++) {
        o4[r].x += acc[r][s] * vv.x;
        o4[r].y += acc[r][s] * vv.y;
        o4[r].z += acc[r][s] * vv.z;
        o4[r].w += acc[r][s] * vv.w;
      }
    }
#pragma unroll
    for (int r = 0; r < 4; r++)
      ((float4*)(out + rowbase + (size_t)r * HDIM))[i * 64 + lane] = o4[r];
  }
}

// ---------------------------------------------------------------------------
extern "C" void kernel_launch(void* const* d_in, const int* in_sizes, int n_in,
                              void* d_out, int out_size, void* d_ws, size_t ws_size,
                              hipStream_t stream) {
  const float* h_e   = (const float*)d_in[0];  // [4,4096,2048]
  const float* h_l   = (const float*)d_in[1];  // [4,10,2048]
  const float* w_q   = (const float*)d_in[2];  // [2048,2048]
  const float* w_k   = (const float*)d_in[3];
  const float* w_v   = (const float*)d_in[4];
  const float* w_o   = (const float*)d_in[5];
  const float* alpha = (const float*)d_in[6];  // scalar
  float* out = (float*)d_out;

  float* ws      = (float*)d_ws;
  float* k_ws    = ws;             // 81920 floats
  float* v_ws    = ws + 81920;
  float* kk_ws   = ws + 163840;
  float* vo_ws   = ws + 245760;
  float* part_ws = ws + 327680;    // 16*4*10*2048 = 1310720 floats (5.2 MB)

  kv_kernel<<<dim3(256, BDIM), 256, 0, stream>>>(h_l, w_k, w_v, k_ws, v_ws);
  kk_part_kernel<<<dim3(2, 32, BDIM), 256, 0, stream>>>(k_ws, w_q, part_ws);
  vo_kernel<<<dim3(256, BDIM), 256, 0, stream>>>(v_ws, w_o, vo_ws);
  kk_reduce_kernel<<<80, 256, 0, stream>>>(part_ws, kk_ws);
  attn_kernel<<<dim3(256, BDIM), 256, 0, stream>>>(h_e, kk_ws, vo_ws, alpha, out);
}

// Round 2
// 454.687 us; speedup vs baseline: 1.0769x; 1.0769x over previous
//
#include <hip/hip_runtime.h>

#define SDIM 10
#define HDIM 2048
#define LDIM 4096
#define BDIM 4

// 1/sqrt(2048)
#define KSCALE 0.02209708691207961f

// ---------------------------------------------------------------------------
// Kernel 1: k[b,s,o] = sum_h h_l[b,s,h]*w_k[o,h];  v likewise with w_v.
// One wave per (o-pair, b). Wave reads w rows coalesced (lane i -> float4 i),
// butterfly-reduces 20 dots (10 s x 2 o) per matrix.
// ---------------------------------------------------------------------------
__global__ __launch_bounds__(256) void kv_kernel(
    const float* __restrict__ h_l, const float* __restrict__ w_k,
    const float* __restrict__ w_v, float* __restrict__ k_out,
    float* __restrict__ v_out) {
  const int b = blockIdx.y;
  const int wave = threadIdx.x >> 6;
  const int lane = threadIdx.x & 63;
  const int opair = blockIdx.x * 4 + wave;
  const int o0 = opair * 2;

  const float4* hl4 = (const float4*)(h_l + (size_t)b * SDIM * HDIM);
  const float4* wk0 = (const float4*)(w_k + (size_t)o0 * HDIM);
  const float4* wk1 = (const float4*)(w_k + (size_t)(o0 + 1) * HDIM);
  const float4* wv0 = (const float4*)(w_v + (size_t)o0 * HDIM);
  const float4* wv1 = (const float4*)(w_v + (size_t)(o0 + 1) * HDIM);

  float ak0[SDIM], ak1[SDIM], av0[SDIM], av1[SDIM];
#pragma unroll
  for (int s = 0; s < SDIM; s++) { ak0[s] = ak1[s] = av0[s] = av1[s] = 0.f; }

#pragma unroll
  for (int j = 0; j < 8; j++) {
    const int idx = j * 64 + lane;
    const float4 a0 = wk0[idx], a1 = wk1[idx];
    const float4 c0 = wv0[idx], c1 = wv1[idx];
#pragma unroll
    for (int s = 0; s < SDIM; s++) {
      const float4 h = hl4[s * 512 + idx];
      ak0[s] += a0.x * h.x + a0.y * h.y + a0.z * h.z + a0.w * h.w;
      ak1[s] += a1.x * h.x + a1.y * h.y + a1.z * h.z + a1.w * h.w;
      av0[s] += c0.x * h.x + c0.y * h.y + c0.z * h.z + c0.w * h.w;
      av1[s] += c1.x * h.x + c1.y * h.y + c1.z * h.z + c1.w * h.w;
    }
  }
#pragma unroll
  for (int s = 0; s < SDIM; s++) {
#pragma unroll
    for (int d = 1; d < 64; d <<= 1) {
      ak0[s] += __shfl_xor(ak0[s], d);
      ak1[s] += __shfl_xor(ak1[s], d);
      av0[s] += __shfl_xor(av0[s], d);
      av1[s] += __shfl_xor(av1[s], d);
    }
  }
  if (lane == 0) {
#pragma unroll
    for (int s = 0; s < SDIM; s++) {
      const size_t base = ((size_t)b * SDIM + s) * HDIM + o0;
      k_out[base]     = ak0[s];
      k_out[base + 1] = ak1[s];
      v_out[base]     = av0[s];
      v_out[base + 1] = av1[s];
    }
  }
}

// ---------------------------------------------------------------------------
// Kernel 2a: kk partials. kk[b,s,h] = sum_o k[b,s,o]*w_q[o,h].
// ---------------------------------------------------------------------------
#define OSPLIT 16
__global__ __launch_bounds__(256) void kk_part_kernel(
    const float* __restrict__ k_in, const float* __restrict__ w_q,
    float* __restrict__ part) {
  const int b = blockIdx.z;
  const int oc = blockIdx.y >> 1;
  const int s0 = (blockIdx.y & 1) * 5;
  const int f4 = blockIdx.x * 256 + threadIdx.x;  // float4 index in [0,512)

  __shared__ float ksh[5 * 128];
  for (int idx = threadIdx.x; idx < 5 * 128; idx += 256) {
    const int s = idx >> 7, oo = idx & 127;
    ksh[idx] = k_in[((size_t)b * SDIM + s0 + s) * HDIM + oc * 128 + oo];
  }
  __syncthreads();

  float4 acc[5];
#pragma unroll
  for (int s = 0; s < 5; s++) acc[s] = make_float4(0.f, 0.f, 0.f, 0.f);

  const float4* wq4 = (const float4*)w_q;
  for (int oo = 0; oo < 128; oo++) {
    const float4 w = wq4[(size_t)(oc * 128 + oo) * 512 + f4];
#pragma unroll
    for (int s = 0; s < 5; s++) {
      const float kv = ksh[s * 128 + oo];
      acc[s].x += kv * w.x; acc[s].y += kv * w.y;
      acc[s].z += kv * w.z; acc[s].w += kv * w.w;
    }
  }
#pragma unroll
  for (int s = 0; s < 5; s++) {
    ((float4*)part)[(((size_t)oc * BDIM + b) * SDIM + s0 + s) * 512 + f4] = acc[s];
  }
}

// Kernel 2b: reduce 16 partials -> kk. 20480 float4 outputs.
__global__ __launch_bounds__(256) void kk_reduce_kernel(
    const float* __restrict__ part, float* __restrict__ kk_out) {
  const int t = blockIdx.x * 256 + threadIdx.x;  // [0, 20480)
  const float4* p4 = (const float4*)part;
  float4 acc = make_float4(0.f, 0.f, 0.f, 0.f);
#pragma unroll
  for (int p = 0; p < OSPLIT; p++) {
    const float4 v = p4[(size_t)p * 20480 + t];
    acc.x += v.x; acc.y += v.y; acc.z += v.z; acc.w += v.w;
  }
  ((float4*)kk_out)[t] = acc;
}

// ---------------------------------------------------------------------------
// Kernel 3: vo[b,s,o] = sum_h v[b,s,h]*w_o[o,h].
// ---------------------------------------------------------------------------
__global__ __launch_bounds__(256) void vo_kernel(
    const float* __restrict__ v_in, const float* __restrict__ w_o,
    float* __restrict__ vo_out) {
  const int b = blockIdx.y;
  const int wave = threadIdx.x >> 6;
  const int lane = threadIdx.x & 63;
  const int opair = blockIdx.x * 4 + wave;
  const int o0 = opair * 2;

  const float4* vb4 = (const float4*)(v_in + (size_t)b * SDIM * HDIM);
  const float4* wo0 = (const float4*)(w_o + (size_t)o0 * HDIM);
  const float4* wo1 = (const float4*)(w_o + (size_t)(o0 + 1) * HDIM);

  float a0[SDIM], a1[SDIM];
#pragma unroll
  for (int s = 0; s < SDIM; s++) { a0[s] = a1[s] = 0.f; }

#pragma unroll
  for (int j = 0; j < 8; j++) {
    const int idx = j * 64 + lane;
    const float4 w0 = wo0[idx], w1 = wo1[idx];
#pragma unroll
    for (int s = 0; s < SDIM; s++) {
      const float4 h = vb4[s * 512 + idx];
      a0[s] += w0.x * h.x + w0.y * h.y + w0.z * h.z + w0.w * h.w;
      a1[s] += w1.x * h.x + w1.y * h.y + w1.z * h.z + w1.w * h.w;
    }
  }
#pragma unroll
  for (int s = 0; s < SDIM; s++) {
#pragma unroll
    for (int d = 1; d < 64; d <<= 1) {
      a0[s] += __shfl_xor(a0[s], d);
      a1[s] += __shfl_xor(a1[s], d);
    }
  }
  if (lane == 0) {
#pragma unroll
    for (int s = 0; s < SDIM; s++) {
      const size_t base = ((size_t)b * SDIM + s) * HDIM + o0;
      vo_out[base]     = a0[s];
      vo_out[base + 1] = a1[s];
    }
  }
}

// ---------------------------------------------------------------------------
// Kernel 4 (main) v3: 2 rows/wave (VGPR-safe, no spill), but kk/vo staged
// through LDS at BLOCK level: 4 waves share each staged chunk, cutting L2
// re-read traffic 4x (1.31 GB -> 328 MB) and replacing per-wave L2 loads
// with ds_read_b128. Chunks of 2 h-subtiles (10 s x 128 float4 = 20 KB);
// staging is exactly 5 float4 per thread. Accumulation order identical to
// the r=2 baseline -> bitwise-same numerics.
// ---------------------------------------------------------------------------
__global__ __launch_bounds__(256) void attn_kernel(
    const float* __restrict__ h_e, const float* __restrict__ kk,
    const float* __restrict__ vo, const float* __restrict__ alpha_p,
    float* __restrict__ out) {
  const int b = blockIdx.y;
  const int wave = threadIdx.x >> 6;
  const int lane = threadIdx.x & 63;
  const int tid = threadIdx.x;
  const int row0 = blockIdx.x * 8 + wave * 2;
  const float alpha = *alpha_p;
  const float4* kkb = (const float4*)(kk + (size_t)b * SDIM * HDIM);
  const float4* vob = (const float4*)(vo + (size_t)b * SDIM * HDIM);
  const size_t rowbase = ((size_t)b * LDIM + row0) * HDIM;

  __shared__ float4 lds[SDIM * 128];  // 20 KB

  // h_e rows held in registers across both phases (64 VGPR).
  float4 he[2][8];
#pragma unroll
  for (int r = 0; r < 2; r++) {
    const float4* src = (const float4*)(h_e + rowbase + (size_t)r * HDIM);
#pragma unroll
    for (int i = 0; i < 8; i++) he[r][i] = src[i * 64 + lane];
  }

  float acc[2][SDIM];
#pragma unroll
  for (int r = 0; r < 2; r++)
#pragma unroll
    for (int s = 0; s < SDIM; s++) acc[r][s] = 0.f;

  // ---- QK phase: 4 chunks, each = h-subtiles {2j, 2j+1} for all 10 s ----
  float4 st[5];
#pragma unroll
  for (int k = 0; k < 5; k++) {
    const int idx = k * 256 + tid;
    st[k] = kkb[(idx >> 7) * 512 + (idx & 127)];  // j=0: cols [0,128)
  }
#pragma unroll
  for (int j = 0; j < 4; j++) {
    __syncthreads();  // prior chunk fully consumed
#pragma unroll
    for (int k = 0; k < 5; k++) lds[k * 256 + tid] = st[k];
    if (j < 3) {
#pragma unroll
      for (int k = 0; k < 5; k++) {
        const int idx = k * 256 + tid;
        st[k] = kkb[(idx >> 7) * 512 + (j + 1) * 128 + (idx & 127)];
      }
    }
    __syncthreads();  // chunk j staged
#pragma unroll
    for (int ii = 0; ii < 2; ii++) {
      const int i = j * 2 + ii;
#pragma unroll
      for (int s = 0; s < SDIM; s++) {
        const float4 kv = lds[s * 128 + ii * 64 + lane];
#pragma unroll
        for (int r = 0; r < 2; r++)
          acc[r][s] += he[r][i].x * kv.x + he[r][i].y * kv.y +
                       he[r][i].z * kv.z + he[r][i].w * kv.w;
      }
    }
  }

  // ---- scores -> softmax (per-wave, no sync needed) ----
#pragma unroll
  for (int r = 0; r < 2; r++)
#pragma unroll
    for (int s = 0; s < SDIM; s++) {
      float v = acc[r][s];
      v += __shfl_xor(v, 1);
      v += __shfl_xor(v, 2);
      v += __shfl_xor(v, 4);
      v += __shfl_xor(v, 8);
      v += __shfl_xor(v, 16);
      v += __shfl_xor(v, 32);
      acc[r][s] = v * KSCALE;
    }
#pragma unroll
  for (int r = 0; r < 2; r++) {
    float m = acc[r][0];
#pragma unroll
    for (int s = 1; s < SDIM; s++) m = fmaxf(m, acc[r][s]);
    float sum = 0.f;
#pragma unroll
    for (int s = 0; s < SDIM; s++) {
      acc[r][s] = __expf(acc[r][s] - m);
      sum += acc[r][s];
    }
    const float inv = alpha / sum;
#pragma unroll
    for (int s = 0; s < SDIM; s++) acc[r][s] *= inv;
  }

  // ---- PV phase: same chunking over vo; write out per h-subtile ----
#pragma unroll
  for (int k = 0; k < 5; k++) {
    const int idx = k * 256 + tid;
    st[k] = vob[(idx >> 7) * 512 + (idx & 127)];
  }
#pragma unroll
  for (int j = 0; j < 4; j++) {
    __syncthreads();  // QK/prior-PV reads of lds done
#pragma unroll
    for (int k = 0; k < 5; k++) lds[k * 256 + tid] = st[k];
    if (j < 3) {
#pragma unroll
      for (int k = 0; k < 5; k++) {
        const int idx = k * 256 + tid;
        st[k] = vob[(idx >> 7) * 512 + (j + 1) * 128 + (idx & 127)];
      }
    }
    __syncthreads();  // chunk j staged
#pragma unroll
    for (int ii = 0; ii < 2; ii++) {
      const int i = j * 2 + ii;
      float4 o4[2];
#pragma unroll
      for (int r = 0; r < 2; r++) o4[r] = he[r][i];
#pragma unroll
      for (int s = 0; s < SDIM; s++) {
        const float4 vv = lds[s * 128 + ii * 64 + lane];
#pragma unroll
        for (int r = 0; r < 2; r++) {
          o4[r].x += acc[r][s] * vv.x;
          o4[r].y += acc[r][s] * vv.y;
          o4[r].z += acc[r][s] * vv.z;
          o4[r].w += acc[r][s] * vv.w;
        }
      }
#pragma unroll
      for (int r = 0; r < 2; r++)
        ((float4*)(out + rowbase + (size_t)r * HDIM))[i * 64 + lane] = o4[r];
    }
  }
}

// ---------------------------------------------------------------------------
extern "C" void kernel_launch(void* const* d_in, const int* in_sizes, int n_in,
                              void* d_out, int out_size, void* d_ws, size_t ws_size,
                              hipStream_t stream) {
  const float* h_e   = (const float*)d_in[0];  // [4,4096,2048]
  const float* h_l   = (const float*)d_in[1];  // [4,10,2048]
  const float* w_q   = (const float*)d_in[2];  // [2048,2048]
  const float* w_k   = (const float*)d_in[3];
  const float* w_v   = (const float*)d_in[4];
  const float* w_o   = (const float*)d_in[5];
  const float* alpha = (const float*)d_in[6];  // scalar
  float* out = (float*)d_out;

  float* ws      = (float*)d_ws;
  float* k_ws    = ws;             // 81920 floats
  float* v_ws    = ws + 81920;
  float* kk_ws   = ws + 163840;
  float* vo_ws   = ws + 245760;
  float* part_ws = ws + 327680;    // 16*4*10*2048 = 1310720 floats (5.2 MB)

  kv_kernel<<<dim3(256, BDIM), 256, 0, stream>>>(h_l, w_k, w_v, k_ws, v_ws);
  kk_part_kernel<<<dim3(2, 32, BDIM), 256, 0, stream>>>(k_ws, w_q, part_ws);
  vo_kernel<<<dim3(256, BDIM), 256, 0, stream>>>(v_ws, w_o, vo_ws);
  kk_reduce_kernel<<<80, 256, 0, stream>>>(part_ws, kk_ws);
  attn_kernel<<<dim3(512, BDIM), 256, 0, stream>>>(h_e, kk_ws, vo_ws, alpha, out);
}